// Round 3
// baseline (355.571 us; speedup 1.0000x reference)
//
#include <hip/hip_runtime.h>

#define EPS 1e-5f

static __device__ __forceinline__ unsigned short f2bf(float f) {
  unsigned int u = __float_as_uint(f);
  u = u + 0x7FFFu + ((u >> 16) & 1u);   // round-nearest-even
  return (unsigned short)(u >> 16);
}
static __device__ __forceinline__ float bf2f(unsigned short h) {
  return __uint_as_float(((unsigned int)h) << 16);
}

// K1: per original point n, compute
//   Z[n, 0:64]  = x[n] @ W1[3:67]              (stored bf16)
//   Y[n, 0:128] = relu(bn(x[n] @ Wl))          (stored bf16)
// Thread-per-row; x row in registers; W accessed with wave-uniform indices
// so the compiler emits scalar (s_load) reads on the SMEM pipe.
__global__ __launch_bounds__(256) void k1_linear(
    const float* __restrict__ x, const float* __restrict__ W1,
    const float* __restrict__ Wl, const float* __restrict__ gl,
    const float* __restrict__ bl, const float* __restrict__ ml,
    const float* __restrict__ vl,
    unsigned short* __restrict__ Z, unsigned short* __restrict__ Y, int N)
{
  int n = blockIdx.x * 256 + threadIdx.x;
  if (n >= N) return;

  float xr[64];
  const float4* xp = reinterpret_cast<const float4*>(x + (size_t)n * 64);
  float4* xr4 = reinterpret_cast<float4*>(xr);
#pragma unroll
  for (int i = 0; i < 16; ++i) xr4[i] = xp[i];

  // ---- Z part: W1 rows 3..66, shape [64 -> 64] ----
  unsigned short* Zr = Z + (size_t)n * 64;
  for (int oc = 0; oc < 64; oc += 4) {
    const float* wb = W1 + 192 + oc;   // (3+i)*64 + oc
    float a0 = 0.f, a1 = 0.f, a2 = 0.f, a3 = 0.f;
#pragma unroll
    for (int i = 0; i < 64; ++i) {
      float4 w = *reinterpret_cast<const float4*>(wb + (size_t)i * 64);
      a0 = fmaf(xr[i], w.x, a0); a1 = fmaf(xr[i], w.y, a1);
      a2 = fmaf(xr[i], w.z, a2); a3 = fmaf(xr[i], w.w, a3);
    }
    *reinterpret_cast<ushort4*>(Zr + oc) =
        make_ushort4(f2bf(a0), f2bf(a1), f2bf(a2), f2bf(a3));
  }

  // ---- Y part: Wl [64 -> 128], then BN + ReLU ----
  unsigned short* Yr = Y + (size_t)n * 128;
  for (int o = 0; o < 128; o += 4) {
    const float* wb = Wl + o;
    float a0 = 0.f, a1 = 0.f, a2 = 0.f, a3 = 0.f;
#pragma unroll
    for (int i = 0; i < 64; ++i) {
      float4 w = *reinterpret_cast<const float4*>(wb + (size_t)i * 128);
      a0 = fmaf(xr[i], w.x, a0); a1 = fmaf(xr[i], w.y, a1);
      a2 = fmaf(xr[i], w.z, a2); a3 = fmaf(xr[i], w.w, a3);
    }
    float s0 = gl[o + 0] * rsqrtf(vl[o + 0] + EPS);
    float s1 = gl[o + 1] * rsqrtf(vl[o + 1] + EPS);
    float s2 = gl[o + 2] * rsqrtf(vl[o + 2] + EPS);
    float s3 = gl[o + 3] * rsqrtf(vl[o + 3] + EPS);
    float t0 = bl[o + 0] - ml[o + 0] * s0;
    float t1 = bl[o + 1] - ml[o + 1] * s1;
    float t2 = bl[o + 2] - ml[o + 2] * s2;
    float t3 = bl[o + 3] - ml[o + 3] * s3;
    a0 = fmaxf(fmaf(a0, s0, t0), 0.f);
    a1 = fmaxf(fmaf(a1, s1, t1), 0.f);
    a2 = fmaxf(fmaf(a2, s2, t2), 0.f);
    a3 = fmaxf(fmaf(a3, s3, t3), 0.f);
    *reinterpret_cast<ushort4*>(Yr + o) =
        make_ushort4(f2bf(a0), f2bf(a1), f2bf(a2), f2bf(a3));
  }
}

// K2: one wave (64 lanes) per sampled center m.
//   lane = channel c for the shrinker MLP (C=64)
//   s[k] = sum_c relu((Z[j] + rel@W1[0:3]) * a1 + c1)[c] * W2[c]   (butterfly)
//   prob = softmax_k(s)   (b2 dropped: softmax is shift-invariant)
//   out[m] = sum_k prob[k] * Y[j_k]   (lane owns channels 2*lane, 2*lane+1)
__global__ __launch_bounds__(256) void k2_gather(
    const float* __restrict__ p, const unsigned short* __restrict__ Z,
    const unsigned short* __restrict__ Y, const float* __restrict__ W1,
    const float* __restrict__ g1, const float* __restrict__ b1,
    const float* __restrict__ m1, const float* __restrict__ v1,
    const float* __restrict__ W2, const int* __restrict__ idx,
    const int* __restrict__ knn, float* __restrict__ out_np,
    float* __restrict__ out_feat, int M)
{
  int gtid = blockIdx.x * 256 + threadIdx.x;
  int wid = gtid >> 6;
  int lane = threadIdx.x & 63;
  if (wid >= M) return;
  int m = __builtin_amdgcn_readfirstlane(wid);

  // per-lane (channel) constants
  float a1 = g1[lane] * rsqrtf(v1[lane] + EPS);
  float c1 = b1[lane] - m1[lane] * a1;
  float w2 = W2[lane];
  float w10 = W1[lane];          // W1 row 0 (rel.x)
  float w11 = W1[64 + lane];     // W1 row 1 (rel.y)
  float w12 = W1[128 + lane];    // W1 row 2 (rel.z)

  int ic = idx[m];               // uniform -> scalar load
  float cx = p[ic * 3 + 0];
  float cy = p[ic * 3 + 1];
  float cz = p[ic * 3 + 2];
  if (lane < 3) {
    float v = (lane == 0) ? cx : ((lane == 1) ? cy : cz);
    out_np[(size_t)m * 3 + lane] = v;
  }

  float s[16];
  int jj[16];
#pragma unroll
  for (int k = 0; k < 16; ++k) {
    int j = knn[m * 16 + k];     // uniform -> scalar load
    jj[k] = j;
    float rx = p[j * 3 + 0] - cx;
    float ry = p[j * 3 + 1] - cy;
    float rz = p[j * 3 + 2] - cz;
    float t = bf2f(Z[(size_t)j * 64 + lane]);   // coalesced 128B row
    t = fmaf(rx, w10, t);
    t = fmaf(ry, w11, t);
    t = fmaf(rz, w12, t);
    float h = fmaxf(fmaf(t, a1, c1), 0.f);
    float part = h * w2;
#pragma unroll
    for (int off = 32; off > 0; off >>= 1)
      part += __shfl_xor(part, off, 64);        // all lanes get the sum
    s[k] = part;
  }

  // softmax over K=16, redundantly in every lane (all in registers)
  float mx = s[0];
#pragma unroll
  for (int k = 1; k < 16; ++k) mx = fmaxf(mx, s[k]);
  float sum = 0.f;
#pragma unroll
  for (int k = 0; k < 16; ++k) { s[k] = __expf(s[k] - mx); sum += s[k]; }
  float inv = 1.f / sum;

  // weighted sum of Y rows; lane owns channels 2*lane and 2*lane+1
  float acc0 = 0.f, acc1 = 0.f;
#pragma unroll
  for (int k = 0; k < 16; ++k) {
    const unsigned short* yr = Y + (size_t)jj[k] * 128;
    unsigned int u = *reinterpret_cast<const unsigned int*>(yr + 2 * lane);
    acc0 = fmaf(s[k], bf2f((unsigned short)(u & 0xFFFFu)), acc0);
    acc1 = fmaf(s[k], bf2f((unsigned short)(u >> 16)), acc1);
  }
  float* orow = out_feat + (size_t)m * 128;
  *reinterpret_cast<float2*>(orow + 2 * lane) =
      make_float2(acc0 * inv, acc1 * inv);
}

extern "C" void kernel_launch(void* const* d_in, const int* in_sizes, int n_in,
                              void* d_out, int out_size, void* d_ws, size_t ws_size,
                              hipStream_t stream) {
  const float* p  = (const float*)d_in[0];
  const float* x  = (const float*)d_in[1];
  const float* W1 = (const float*)d_in[2];
  const float* g1 = (const float*)d_in[3];
  const float* b1 = (const float*)d_in[4];
  const float* m1 = (const float*)d_in[5];
  const float* v1 = (const float*)d_in[6];
  const float* W2 = (const float*)d_in[7];
  // d_in[8] = b2: softmax is shift-invariant -> unused
  const float* Wl = (const float*)d_in[9];
  const float* gl = (const float*)d_in[10];
  const float* bl = (const float*)d_in[11];
  const float* ml = (const float*)d_in[12];
  const float* vl = (const float*)d_in[13];
  const int* idx  = (const int*)d_in[14];
  const int* knn  = (const int*)d_in[15];

  const int N = in_sizes[1] / 64;    // 200000
  const int M = in_sizes[14];        // 50000

  unsigned short* Z = (unsigned short*)d_ws;                  // [N,64]  bf16
  unsigned short* Y = Z + (size_t)N * 64;                     // [N,128] bf16
  float* out_np   = (float*)d_out;                            // [M,3]
  float* out_feat = out_np + (size_t)M * 3;                   // [M,128]

  dim3 blk(256);
  k1_linear<<<dim3((N + 255) / 256), blk, 0, stream>>>(
      x, W1, Wl, gl, bl, ml, vl, Z, Y, N);
  k2_gather<<<dim3(((size_t)M * 64 + 255) / 256), blk, 0, stream>>>(
      p, Z, Y, W1, g1, b1, m1, v1, W2, idx, knn, out_np, out_feat, M);
}

// Round 5
// 219.697 us; speedup vs baseline: 1.6185x; 1.6185x over previous
//
#include <hip/hip_runtime.h>

#define EPS 1e-5f

typedef __attribute__((ext_vector_type(8))) short bf16x8;
typedef __attribute__((ext_vector_type(4))) float f32x4;

static __device__ __forceinline__ unsigned short f2bf(float f) {
  unsigned int u = __float_as_uint(f);
  u = u + 0x7FFFu + ((u >> 16) & 1u);   // round-nearest-even
  return (unsigned short)(u >> 16);
}
static __device__ __forceinline__ float bf2f(unsigned short h) {
  return __uint_as_float(((unsigned int)h) << 16);
}
static __device__ __forceinline__ unsigned int pk2(float lo, float hi) {
  return (unsigned int)f2bf(lo) | ((unsigned int)f2bf(hi) << 16);
}

// K1 (MFMA): C[200000 x 192] = x[200000 x 64] @ [W1[3:67] | Wl], split-stored:
//   cols 0..63   -> Z bf16 (raw)
//   cols 64..191 -> Y bf16 (BN + ReLU fused)
// BM=64, BN=192, K=64 fully LDS-resident. 4 waves/block; wave w owns
// rows (w&1)*32, cols (w>>1)*96. LDS tiles swizzled: byte ^= (row&7)<<4
// (G4 fix for 128B-stride rows on ds_read_b128).
__global__ __launch_bounds__(256) void k1_mfma(
    const float* __restrict__ x, const float* __restrict__ W1,
    const float* __restrict__ Wl, const float* __restrict__ gl,
    const float* __restrict__ bl, const float* __restrict__ ml,
    const float* __restrict__ vl,
    unsigned short* __restrict__ Z, unsigned short* __restrict__ Y)
{
  __shared__ unsigned short As[64 * 64];    // [row][k]  8 KB
  __shared__ unsigned short Bs[192 * 64];   // [col][k] 24 KB
  char* Ab = reinterpret_cast<char*>(As);
  char* Bb = reinterpret_cast<char*>(Bs);

  const int t = threadIdx.x;
  const long row0 = (long)blockIdx.x * 64;

  // ---- stage B: W1 rows 3..66 -> Bs[c][k], c=0..63 ----
  {
    int k = t >> 2, c0 = (t & 3) * 16;
    const float4* w4 = reinterpret_cast<const float4*>(W1 + (size_t)(3 + k) * 64 + c0);
#pragma unroll
    for (int i = 0; i < 4; ++i) {
      float4 w = w4[i];
#pragma unroll
      for (int j = 0; j < 4; ++j) {
        int c = c0 + i * 4 + j;
        float v = (j == 0) ? w.x : (j == 1) ? w.y : (j == 2) ? w.z : w.w;
        int byte = c * 128 + ((2 * k) ^ ((c & 7) << 4));
        *reinterpret_cast<unsigned short*>(Bb + byte) = f2bf(v);
      }
    }
  }
  // ---- stage B: Wl[k][c] -> Bs[64+c][k], c=0..127 ----
  {
    int k = t >> 2, c0 = (t & 3) * 32;
    const float4* w4 = reinterpret_cast<const float4*>(Wl + (size_t)k * 128 + c0);
#pragma unroll
    for (int i = 0; i < 8; ++i) {
      float4 w = w4[i];
#pragma unroll
      for (int j = 0; j < 4; ++j) {
        int c = 64 + c0 + i * 4 + j;
        float v = (j == 0) ? w.x : (j == 1) ? w.y : (j == 2) ? w.z : w.w;
        int byte = c * 128 + ((2 * k) ^ ((c & 7) << 4));
        *reinterpret_cast<unsigned short*>(Bb + byte) = f2bf(v);
      }
    }
  }
  // ---- stage A: x rows row0..row0+63 (fp32 -> bf16) ----
  {
    const float4* xg = reinterpret_cast<const float4*>(x + row0 * 64);
#pragma unroll
    for (int i = 0; i < 4; ++i) {
      int idx = t + i * 256;            // float4 index in 64x64 tile
      float4 v = xg[idx];               // fully coalesced
      int r = idx >> 4;                 // 16 float4 per row
      int b0 = (idx & 15) * 8;          // bf16 byte offset in row
      int byte = r * 128 + (b0 ^ ((r & 7) << 4));  // 8B chunk stays in 16B slot
      uint2 pk = make_uint2(pk2(v.x, v.y), pk2(v.z, v.w));
      *reinterpret_cast<uint2*>(Ab + byte) = pk;
    }
  }
  __syncthreads();

  const int wid = t >> 6, lane = t & 63;
  const int roff = (wid & 1) * 32, coff = (wid >> 1) * 96;
  const int lr = lane & 15, lk = lane >> 4;   // frag row/col, k-group

  // A fragments: row = roff + rt*16 + lr, k = ks*32 + lk*8 + i
  bf16x8 af[2][2];
#pragma unroll
  for (int rt = 0; rt < 2; ++rt) {
    int r = roff + rt * 16 + lr;
#pragma unroll
    for (int ks = 0; ks < 2; ++ks) {
      int byte = r * 128 + ((ks * 64 + lk * 16) ^ ((r & 7) << 4));
      af[rt][ks] = *reinterpret_cast<const bf16x8*>(Ab + byte);
    }
  }

#pragma unroll
  for (int ct = 0; ct < 6; ++ct) {
    int c = coff + ct * 16 + lr;        // global output col (0..191)
    int byte0 = c * 128 + ((lk * 16) ^ ((c & 7) << 4));
    int byte1 = c * 128 + ((64 + lk * 16) ^ ((c & 7) << 4));
    bf16x8 bf0 = *reinterpret_cast<const bf16x8*>(Bb + byte0);
    bf16x8 bf1 = *reinterpret_cast<const bf16x8*>(Bb + byte1);

    float sc = 1.f, sh = 0.f;
    if (c >= 64) {                      // BN constants for Y columns
      int oc = c - 64;
      sc = gl[oc] * rsqrtf(vl[oc] + EPS);
      sh = bl[oc] - ml[oc] * sc;
    }
#pragma unroll
    for (int rt = 0; rt < 2; ++rt) {
      f32x4 acc = {0.f, 0.f, 0.f, 0.f};
      acc = __builtin_amdgcn_mfma_f32_16x16x32_bf16(af[rt][0], bf0, acc, 0, 0, 0);
      acc = __builtin_amdgcn_mfma_f32_16x16x32_bf16(af[rt][1], bf1, acc, 0, 0, 0);
      long grow = row0 + roff + rt * 16 + lk * 4;   // + q
      if (c < 64) {
#pragma unroll
        for (int q = 0; q < 4; ++q)
          Z[(grow + q) * 64 + c] = f2bf(acc[q]);
      } else {
        int oc = c - 64;
#pragma unroll
        for (int q = 0; q < 4; ++q) {
          float yv = fmaxf(fmaf(acc[q], sc, sh), 0.f);
          Y[(grow + q) * 128 + oc] = f2bf(yv);
        }
      }
    }
  }
}

// K2: one wave (64 lanes) per sampled center m.  (unchanged this round)
__global__ __launch_bounds__(256) void k2_gather(
    const float* __restrict__ p, const unsigned short* __restrict__ Z,
    const unsigned short* __restrict__ Y, const float* __restrict__ W1,
    const float* __restrict__ g1, const float* __restrict__ b1,
    const float* __restrict__ m1, const float* __restrict__ v1,
    const float* __restrict__ W2, const int* __restrict__ idx,
    const int* __restrict__ knn, float* __restrict__ out_np,
    float* __restrict__ out_feat, int M)
{
  int gtid = blockIdx.x * 256 + threadIdx.x;
  int wid = gtid >> 6;
  int lane = threadIdx.x & 63;
  if (wid >= M) return;
  int m = __builtin_amdgcn_readfirstlane(wid);

  float a1 = g1[lane] * rsqrtf(v1[lane] + EPS);
  float c1 = b1[lane] - m1[lane] * a1;
  float w2 = W2[lane];
  float w10 = W1[lane];
  float w11 = W1[64 + lane];
  float w12 = W1[128 + lane];

  int ic = idx[m];
  float cx = p[ic * 3 + 0];
  float cy = p[ic * 3 + 1];
  float cz = p[ic * 3 + 2];
  if (lane < 3) {
    float v = (lane == 0) ? cx : ((lane == 1) ? cy : cz);
    out_np[(size_t)m * 3 + lane] = v;
  }

  float s[16];
  int jj[16];
#pragma unroll
  for (int k = 0; k < 16; ++k) {
    int j = knn[m * 16 + k];
    jj[k] = j;
    float rx = p[j * 3 + 0] - cx;
    float ry = p[j * 3 + 1] - cy;
    float rz = p[j * 3 + 2] - cz;
    float tv = bf2f(Z[(size_t)j * 64 + lane]);
    tv = fmaf(rx, w10, tv);
    tv = fmaf(ry, w11, tv);
    tv = fmaf(rz, w12, tv);
    float h = fmaxf(fmaf(tv, a1, c1), 0.f);
    float part = h * w2;
#pragma unroll
    for (int off = 32; off > 0; off >>= 1)
      part += __shfl_xor(part, off, 64);
    s[k] = part;
  }

  float mx = s[0];
#pragma unroll
  for (int k = 1; k < 16; ++k) mx = fmaxf(mx, s[k]);
  float sum = 0.f;
#pragma unroll
  for (int k = 0; k < 16; ++k) { s[k] = __expf(s[k] - mx); sum += s[k]; }
  float inv = 1.f / sum;

  float acc0 = 0.f, acc1 = 0.f;
#pragma unroll
  for (int k = 0; k < 16; ++k) {
    const unsigned short* yr = Y + (size_t)jj[k] * 128;
    unsigned int u = *reinterpret_cast<const unsigned int*>(yr + 2 * lane);
    acc0 = fmaf(s[k], bf2f((unsigned short)(u & 0xFFFFu)), acc0);
    acc1 = fmaf(s[k], bf2f((unsigned short)(u >> 16)), acc1);
  }
  float* orow = out_feat + (size_t)m * 128;
  *reinterpret_cast<float2*>(orow + 2 * lane) =
      make_float2(acc0 * inv, acc1 * inv);
}

extern "C" void kernel_launch(void* const* d_in, const int* in_sizes, int n_in,
                              void* d_out, int out_size, void* d_ws, size_t ws_size,
                              hipStream_t stream) {
  const float* p  = (const float*)d_in[0];
  const float* x  = (const float*)d_in[1];
  const float* W1 = (const float*)d_in[2];
  const float* g1 = (const float*)d_in[3];
  const float* b1 = (const float*)d_in[4];
  const float* m1 = (const float*)d_in[5];
  const float* v1 = (const float*)d_in[6];
  const float* W2 = (const float*)d_in[7];
  // d_in[8] = b2: softmax shift-invariant -> unused
  const float* Wl = (const float*)d_in[9];
  const float* gl = (const float*)d_in[10];
  const float* bl = (const float*)d_in[11];
  const float* ml = (const float*)d_in[12];
  const float* vl = (const float*)d_in[13];
  const int* idx  = (const int*)d_in[14];
  const int* knn  = (const int*)d_in[15];

  const int N = in_sizes[1] / 64;    // 200000 (divisible by 64)
  const int M = in_sizes[14];        // 50000

  unsigned short* Z = (unsigned short*)d_ws;                  // [N,64]  bf16
  unsigned short* Y = Z + (size_t)N * 64;                     // [N,128] bf16
  float* out_np   = (float*)d_out;                            // [M,3]
  float* out_feat = out_np + (size_t)M * 3;                   // [M,128]

  k1_mfma<<<dim3(N / 64), dim3(256), 0, stream>>>(
      x, W1, Wl, gl, bl, ml, vl, Z, Y);
  k2_gather<<<dim3(((size_t)M * 64 + 255) / 256), dim3(256), 0, stream>>>(
      p, Z, Y, W1, g1, b1, m1, v1, W2, idx, knn, out_np, out_feat, M);
}